// Round 13
// baseline (73.275 us; speedup 1.0000x reference)
//
#include <hip/hip_runtime.h>

#define HH 512
#define WW 512
#define NB 16
#define NTOT (NB * 3 * HH * WW)     // 12582912
#define CHS (HH * WW)               // 262144, CHS % 3 == 1

// 4-wide x 8-tall strips, no LDS (except reduction). Rolling 2-row history.
// R13 "share-B": per row/channel/array each lane loads ONE float4 (its own 4
// cols); window halo floats come from shfl_up/down(B,1,32) since lane i's
// left chunk == lane i-1's B. Lanes tx==0/31 patch outer halo via exec-masked
// loads. Cuts L1 traffic 3x vs R10 (18 -> 6 full-width loads/row).
// ycc[f] = x[f-j]*mat[0][j] + x[f-j+1]*mat[1][j] + x[f-j+2]*mat[2][j] + bias[j],
// j = f % 3 (reference's reshape(-1,3) @ mat over flat NCHW memory).
// 5-tap rotated-coef scheme (R8) + exp-folded norm consts (R10).
// KEEP rolled `#pragma unroll 1` loop (R6: full unroll = 256 VGPR + spills).
// KEEP VGPR <= 128 (R9/R11: >128 -> occupancy halves -> big regression).
// KEEP 512 blocks / 2 waves per SIMD (R12: 1 wave/SIMD -> +11%).

#define SC2 (-0.0072134752044448f)  // -1/(2*sigma^2) * log2(e), sigma=10

#if __has_builtin(__builtin_amdgcn_exp2f)
#define EXP2(v) __builtin_amdgcn_exp2f(v)
#else
#define EXP2(v) exp2f(v)
#endif

__device__ __forceinline__ int mod3s(int v) { return v >= 3 ? v - 3 : v; }

__device__ __forceinline__ void build_rot(int mrow, float (&Rc)[3][5], float (&Rb)[3])
{
    constexpr float T[3][5] = {
        { 0.f,     0.f,     0.257f, 0.564f, 0.098f },   // j=0
        { 0.f,    -0.148f, -0.291f, 0.439f, 0.f    },   // j=1
        { 0.439f, -0.368f, -0.071f, 0.f,    0.f    } }; // j=2
    constexpr float Tb[3] = { 16.f/255.f, 128.f/255.f, 128.f/255.f };
    const bool is1 = (mrow == 1);
    const bool is2 = (mrow == 2);
#pragma unroll
    for (int p = 0; p < 3; ++p) {
#pragma unroll
        for (int s = 0; s < 5; ++s) {
            const float v0 = T[p][s], v1 = T[(p+1)%3][s], v2 = T[(p+2)%3][s];
            Rc[p][s] = is1 ? v1 : (is2 ? v2 : v0);
        }
        Rb[p] = is1 ? Tb[(p+1)%3] : (is2 ? Tb[(p+2)%3] : Tb[p]);
    }
}

// Per channel: load own float4 (window cols 4..7), assemble the 12-float x
// window + 8-col o window via cross-lane shuffles; edge lanes patch via
// exec-masked loads. Then 5-tap ycc for all 8 window centers.
template<bool EDGE>
__device__ __forceinline__ void load_make(const float* __restrict__ x,
                                          const float* __restrict__ op,
                                          int fbase, int tx,
                                          const float (&Rc)[3][5], const float (&Rb)[3],
                                          float (&yc)[3][8], float (&oc)[3][8])
{
#pragma unroll
    for (int c = 0; c < 3; ++c) {
        const int fb = fbase + c * CHS;
        int aB = fb + 4;
        if (EDGE) aB = min(max(aB, 0), NTOT - 4);
        const float4 Bx = *(const float4*)(x + aB);
        const float4 Bo = *(const float4*)(op + aB);

        float xw[12];
        xw[4] = Bx.x; xw[5] = Bx.y; xw[6] = Bx.z; xw[7] = Bx.w;
        // halo via neighbor's B (segments of 32 = tx rows)
        xw[0]  = __shfl_up(Bx.x, 1, 32);
        xw[1]  = __shfl_up(Bx.y, 1, 32);
        xw[2]  = __shfl_up(Bx.z, 1, 32);
        xw[3]  = __shfl_up(Bx.w, 1, 32);
        xw[8]  = __shfl_down(Bx.x, 1, 32);
        xw[9]  = __shfl_down(Bx.y, 1, 32);
        xw[10] = __shfl_down(Bx.z, 1, 32);
        xw[11] = __shfl_down(Bx.w, 1, 32);
        float oc0 = __shfl_up(Bo.z, 1, 32);
        float oc1 = __shfl_up(Bo.w, 1, 32);
        float oc6 = __shfl_down(Bo.x, 1, 32);
        float oc7 = __shfl_down(Bo.y, 1, 32);

        if (tx == 0) {              // patch left halo (outside wave coverage)
            int aA = fb;
            if (EDGE) aA = min(max(aA, 0), NTOT - 4);
            const float4 Ax = *(const float4*)(x + aA);
            const float4 Ao = *(const float4*)(op + aA);
            xw[0] = Ax.x; xw[1] = Ax.y; xw[2] = Ax.z; xw[3] = Ax.w;
            oc0 = Ao.z; oc1 = Ao.w;
        }
        if (tx == 31) {             // patch right halo
            int aC = fb + 8;
            if (EDGE) aC = min(max(aC, 0), NTOT - 4);
            const float4 Cx = *(const float4*)(x + aC);
            const float4 Co = *(const float4*)(op + aC);
            xw[8] = Cx.x; xw[9] = Cx.y; xw[10] = Cx.z; xw[11] = Cx.w;
            oc6 = Co.x; oc7 = Co.y;
        }

        oc[c][0] = oc0; oc[c][1] = oc1;
        oc[c][2] = Bo.x; oc[c][3] = Bo.y; oc[c][4] = Bo.z; oc[c][5] = Bo.w;
        oc[c][6] = oc6; oc[c][7] = oc7;

#pragma unroll
        for (int k = 0; k < 8; ++k) {
            const int q = (c + k + 2) % 3;         // static after unroll
            float a = Rb[q];
#pragma unroll
            for (int s = 0; s < 5; ++s)
                a = fmaf(xw[k + s], Rc[q][s], a);
            yc[c][k] = a;
        }
    }
}

__device__ __forceinline__ void stash(float (&yb)[3][4], float (&ob)[3][4],
                                      const float (&yc)[3][8], const float (&oc)[3][8])
{
#pragma unroll
    for (int c = 0; c < 3; ++c)
#pragma unroll
        for (int p = 0; p < 4; ++p) { yb[c][p] = yc[c][p+2]; ob[c][p] = oc[c][p+2]; }
}

template<bool EDGE>
__device__ __forceinline__ void pairs_dy0(const float (&yc)[3][8], const float (&oc)[3][8],
                                          const bool (&cv)[8], float& acc)
{
    constexpr float L0[3] = { 0.f, -20.99717945f, -20.99435343f }; // [adx]
#pragma unroll
    for (int dx = 1; dx <= 2; ++dx) {
        const float L = L0[dx];
#pragma unroll
        for (int p = 0; p < 4; ++p) {
            const int k = p + dx + 2, kb = p + 2;
            const float d0 = yc[0][k] - yc[0][kb];
            const float d1 = yc[1][k] - yc[1][kb];
            const float d2 = yc[2][k] - yc[2][kb];
            const float ss = fmaf(d2, d2, fmaf(d1, d1, d0 * d0));
            const float sad = fabsf(oc[0][k] - oc[0][kb]) + fabsf(oc[1][k] - oc[1][kb])
                            + fabsf(oc[2][k] - oc[2][kb]);
            const float sadm = (!EDGE || cv[k]) ? sad : 0.f;
            acc = fmaf(EXP2(fmaf(SC2, ss, L)), sadm, acc);
        }
    }
}

template<int DY, bool EDGE>
__device__ __forceinline__ void pairs_dyn(const float (&yc)[3][8], const float (&oc)[3][8],
                                          const float (&yb)[3][4], const float (&ob)[3][4],
                                          const bool (&cv)[8], float& acc)
{
    constexpr float L1[3] = { -20.99717945f, -20.99435890f, -20.99153288f }; // dy=1,[adx]
    constexpr float L2[3] = { -20.99435343f, -20.99153288f, -20.98870686f }; // dy=2,[adx]
#pragma unroll
    for (int dx = -2; dx <= 2; ++dx) {
        const int adx = dx < 0 ? -dx : dx;
        const float L = (DY == 1) ? L1[adx] : L2[adx];
#pragma unroll
        for (int p = 0; p < 4; ++p) {
            const int k = p + dx + 2;              // 0..7
            const float d0 = yc[0][k] - yb[0][p];
            const float d1 = yc[1][k] - yb[1][p];
            const float d2 = yc[2][k] - yb[2][p];
            const float ss = fmaf(d2, d2, fmaf(d1, d1, d0 * d0));
            const float sad = fabsf(oc[0][k] - ob[0][p]) + fabsf(oc[1][k] - ob[1][p])
                            + fabsf(oc[2][k] - ob[2][p]);
            const float sadm = (!EDGE || cv[k]) ? sad : 0.f;
            acc = fmaf(EXP2(fmaf(SC2, ss, L)), sadm, acc);
        }
    }
}

template<bool EDGE>
__device__ __forceinline__ float run_strip(const float* __restrict__ x,
                                           const float* __restrict__ op,
                                           int wq, int rb, int b, int tx)
{
    bool cv[8];
#pragma unroll
    for (int k = 0; k < 8; ++k) cv[k] = !EDGE || ((unsigned)(wq - 2 + k) < (unsigned)WW);

    const int fb0 = (b * 3 * HH + rb) * WW + (wq - 4);   // c=0, s=0 window base
    int mrow = (2 * rb + wq + 2) % 3;                    // fb0 % 3 (nonneg form)

    float Rc[3][5], Rb[3];
    float yp[2][3][4], opv[2][3][4];
    float yc[3][8], oc[3][8];
    float acc0 = 0.f, acc1 = 0.f;

    // ---- s = 0 ----
    build_rot(mrow, Rc, Rb);
    load_make<EDGE>(x, op, fb0, tx, Rc, Rb, yc, oc);
    pairs_dy0<EDGE>(yc, oc, cv, acc0);
    stash(yp[0], opv[0], yc, oc);
    // ---- s = 1 ----
    mrow = mod3s(mrow + 2);
    build_rot(mrow, Rc, Rb);
    load_make<EDGE>(x, op, fb0 + WW, tx, Rc, Rb, yc, oc);
    pairs_dy0<EDGE>(yc, oc, cv, acc0);
    pairs_dyn<1, EDGE>(yc, oc, yp[0], opv[0], cv, acc1);
    stash(yp[1], opv[1], yc, oc);

#pragma unroll 1
    for (int s = 2; s < 10; s += 2) {
        // ---- row A = s: slot0 holds s-2, slot1 holds s-1 ----
        mrow = mod3s(mrow + 2);
        build_rot(mrow, Rc, Rb);
        const bool rokA = !EDGE || (rb + s) < HH;
        load_make<EDGE>(x, op, fb0 + s * WW, tx, Rc, Rb, yc, oc);
        if (s < 8) pairs_dy0<EDGE>(yc, oc, cv, acc0);
        if (rokA) {
            pairs_dyn<1, EDGE>(yc, oc, yp[1], opv[1], cv, acc0);   // base row s-1
            pairs_dyn<2, EDGE>(yc, oc, yp[0], opv[0], cv, acc1);   // base row s-2
        }
        if (s < 8) stash(yp[0], opv[0], yc, oc);
        // ---- row B = s+1: slot0 holds s, slot1 holds s-1 ----
        mrow = mod3s(mrow + 2);
        build_rot(mrow, Rc, Rb);
        const bool rokB = !EDGE || (rb + s + 1) < HH;
        load_make<EDGE>(x, op, fb0 + (s + 1) * WW, tx, Rc, Rb, yc, oc);
        if (s + 1 < 8) pairs_dy0<EDGE>(yc, oc, cv, acc0);
        if (rokB) {
            if (s < 8) pairs_dyn<1, EDGE>(yc, oc, yp[0], opv[0], cv, acc0);  // base row s
            pairs_dyn<2, EDGE>(yc, oc, yp[1], opv[1], cv, acc1);             // base row s-1
        }
        if (s + 1 < 8) stash(yp[1], opv[1], yc, oc);
    }

    return acc0 + acc1;
}

__global__ __launch_bounds__(256)
void smooth_loss_kernel(const float* __restrict__ x, const float* __restrict__ op,
                        float* __restrict__ total)
{
    const int tx  = threadIdx.x;                    // 0..31
    const int ty  = threadIdx.y;                    // 0..7
    const int tid = ty * 32 + tx;
    const int bx  = blockIdx.x, by = blockIdx.y, b = blockIdx.z;
    const int wq  = bx * 128 + 4 * tx;              // first owned col
    const int rb  = by * 64 + 8 * ty;               // first owned row (<= 504)

    // interior blocks (44%): windows never touch image edges -> no clamps/selects
    float acc;
    if ((bx == 1 || bx == 2) && by < 7)             // block-uniform branch
        acc = run_strip<false>(x, op, wq, rb, b, tx);
    else
        acc = run_strip<true>(x, op, wq, rb, b, tx);

    // ---- reduction: wave shuffle -> LDS -> one atomic per block ----
#pragma unroll
    for (int off = 32; off > 0; off >>= 1)
        acc += __shfl_down(acc, off, 64);

    __shared__ float s_part[4];
    if ((tid & 63) == 0) s_part[tid >> 6] = acc;
    __syncthreads();
    if (tid == 0)
        atomicAdd(total, s_part[0] + s_part[1] + s_part[2] + s_part[3]);
}

extern "C" void kernel_launch(void* const* d_in, const int* in_sizes, int n_in,
                              void* d_out, int out_size, void* d_ws, size_t ws_size,
                              hipStream_t stream) {
    const float* x  = (const float*)d_in[0];   // "input"  [16,3,512,512] fp32
    const float* op = (const float*)d_in[1];   // "output" [16,3,512,512] fp32
    float* total = (float*)d_out;              // scalar fp32

    hipMemsetAsync(total, 0, sizeof(float), stream);

    dim3 grid(4, 8, NB);                       // 512 blocks (2/CU)
    dim3 block(32, 8);                         // 256 threads; strip 4x8 each
    smooth_loss_kernel<<<grid, block, 0, stream>>>(x, op, total);
}

// Round 14
// 59.494 us; speedup vs baseline: 1.2316x; 1.2316x over previous
//
#include <hip/hip_runtime.h>

#define HH 512
#define WW 512
#define NB 16
#define NTOT (NB * 3 * HH * WW)     // 12582912
#define CHS (HH * WW)               // 262144, CHS % 3 == 1

// 4-wide x 8-tall strips. R14: x-row staging via global_load_lds (zero-VGPR
// prefetch). Per wave-private LDS buffers (no barriers): stage row s+1 into
// buf^1 while computing row s from buf. Counted s_waitcnt vmcnt(18) = {o(s) 9
// + stage(s+1) 9} in flight, stage(s) retired (vmcnt retires in order).
// o-loads stay direct-to-VGPR (wait lands at oc copy, covered by stage+dsread).
// ycc 5-tap rotated-coef (R8), exp-folded norm consts (R10).
// KEEP rolled `#pragma unroll 1` loop (R6: full unroll spills).
// KEEP VGPR <= 128 (R9/R11/R13: >128 -> occupancy halves -> regression).
// KEEP 512 blocks / 2 per CU (R12: 1 wave/SIMD hurts).

#define SC2 (-0.0072134752044448f)  // -1/(2*sigma^2) * log2(e), sigma=10

#if __has_builtin(__builtin_amdgcn_exp2f)
#define EXP2(v) __builtin_amdgcn_exp2f(v)
#else
#define EXP2(v) exp2f(v)
#endif

#define GLD_LDS(g, l) __builtin_amdgcn_global_load_lds(                      \
    (const __attribute__((address_space(1))) void*)(g),                      \
    (__attribute__((address_space(3))) void*)(l), 16, 0, 0)

__device__ __forceinline__ int mod3s(int v) { return v >= 3 ? v - 3 : v; }

__device__ __forceinline__ void build_rot(int mrow, float (&Rc)[3][5], float (&Rb)[3])
{
    constexpr float T[3][5] = {
        { 0.f,     0.f,     0.257f, 0.564f, 0.098f },   // j=0
        { 0.f,    -0.148f, -0.291f, 0.439f, 0.f    },   // j=1
        { 0.439f, -0.368f, -0.071f, 0.f,    0.f    } }; // j=2
    constexpr float Tb[3] = { 16.f/255.f, 128.f/255.f, 128.f/255.f };
    const bool is1 = (mrow == 1);
    const bool is2 = (mrow == 2);
#pragma unroll
    for (int p = 0; p < 3; ++p) {
#pragma unroll
        for (int s = 0; s < 5; ++s) {
            const float v0 = T[p][s], v1 = T[(p+1)%3][s], v2 = T[(p+2)%3][s];
            Rc[p][s] = is1 ? v1 : (is2 ? v2 : v0);
        }
        Rb[p] = is1 ? Tb[(p+1)%3] : (is2 ? Tb[(p+2)%3] : Tb[p]);
    }
}

// async-stage one row's 9 x-chunks: lane's 16B lands at sb[q][lane]
template<bool EDGE>
__device__ __forceinline__ void stage_x(const float* __restrict__ x, int fbase,
                                        float4 (&sb)[9][64])
{
#pragma unroll
    for (int c = 0; c < 3; ++c) {
        const int fb = fbase + c * CHS;
        int f0 = fb, f1 = fb + 4, f2 = fb + 8;
        if (EDGE) {
            f0 = min(max(f0, 0), NTOT - 4);
            f1 = min(max(f1, 0), NTOT - 4);
            f2 = min(max(f2, 0), NTOT - 4);
        }
        GLD_LDS(x + f0, &sb[3 * c + 0][0]);
        GLD_LDS(x + f1, &sb[3 * c + 1][0]);
        GLD_LDS(x + f2, &sb[3 * c + 2][0]);
    }
}

template<bool EDGE>
__device__ __forceinline__ void load_o(const float* __restrict__ op, int fbase,
                                       float (&ow)[3][12])
{
#pragma unroll
    for (int c = 0; c < 3; ++c) {
        const int fb = fbase + c * CHS;
        int f0 = fb, f1 = fb + 4, f2 = fb + 8;
        if (EDGE) {
            f0 = min(max(f0, 0), NTOT - 4);
            f1 = min(max(f1, 0), NTOT - 4);
            f2 = min(max(f2, 0), NTOT - 4);
        }
        *(float4*)&ow[c][0] = *(const float4*)(op + f0);
        *(float4*)&ow[c][4] = *(const float4*)(op + f1);
        *(float4*)&ow[c][8] = *(const float4*)(op + f2);
    }
}

// ds_read the staged row + ycc 5-tap; oc copied from ow (o-wait lands here)
__device__ __forceinline__ void read_make(const float4 (&sb)[9][64], int lane,
                                          const float (&Rc)[3][5], const float (&Rb)[3],
                                          const float (&ow)[3][12],
                                          float (&yc)[3][8], float (&oc)[3][8])
{
    float xw[3][12];
#pragma unroll
    for (int q = 0; q < 9; ++q)
        *(float4*)&xw[q / 3][4 * (q % 3)] = sb[q][lane];
#pragma unroll
    for (int c = 0; c < 3; ++c) {
#pragma unroll
        for (int k = 0; k < 8; ++k) {
            const int q = (c + k + 2) % 3;         // static after unroll
            float a = Rb[q];
#pragma unroll
            for (int s = 0; s < 5; ++s)
                a = fmaf(xw[c][k + s], Rc[q][s], a);
            yc[c][k] = a;
            oc[c][k] = ow[c][k + 2];
        }
    }
}

// one row phase: issue o(s), issue stage(s+1)->bufW, counted wait, consume bufR
template<bool EDGE>
__device__ __forceinline__ void row_phase(const float* __restrict__ x,
                                          const float* __restrict__ op,
                                          int fb0, int sRow, int sNext,
                                          float4 (&bufR)[9][64], float4 (&bufW)[9][64],
                                          const float (&Rc)[3][5], const float (&Rb)[3],
                                          float (&yc)[3][8], float (&oc)[3][8], int lane)
{
    float ow[3][12];
    load_o<EDGE>(op, fb0 + sRow * WW, ow);            // oldest 9 this phase
    __builtin_amdgcn_sched_barrier(0);
    stage_x<EDGE>(x, fb0 + sNext * WW, bufW);         // newest 9 (survive o-waits)
    __builtin_amdgcn_sched_barrier(0);
    asm volatile("s_waitcnt vmcnt(18)" ::: "memory"); // stage(sRow) retired
    __builtin_amdgcn_sched_barrier(0);
    read_make(bufR, lane, Rc, Rb, ow, yc, oc);
}

__device__ __forceinline__ void stash(float (&yb)[3][4], float (&ob)[3][4],
                                      const float (&yc)[3][8], const float (&oc)[3][8])
{
#pragma unroll
    for (int c = 0; c < 3; ++c)
#pragma unroll
        for (int p = 0; p < 4; ++p) { yb[c][p] = yc[c][p+2]; ob[c][p] = oc[c][p+2]; }
}

template<bool EDGE>
__device__ __forceinline__ void pairs_dy0(const float (&yc)[3][8], const float (&oc)[3][8],
                                          const bool (&cv)[8], float& acc)
{
    constexpr float L0[3] = { 0.f, -20.99717945f, -20.99435343f }; // [adx]
#pragma unroll
    for (int dx = 1; dx <= 2; ++dx) {
        const float L = L0[dx];
#pragma unroll
        for (int p = 0; p < 4; ++p) {
            const int k = p + dx + 2, kb = p + 2;
            const float d0 = yc[0][k] - yc[0][kb];
            const float d1 = yc[1][k] - yc[1][kb];
            const float d2 = yc[2][k] - yc[2][kb];
            const float ss = fmaf(d2, d2, fmaf(d1, d1, d0 * d0));
            const float sad = fabsf(oc[0][k] - oc[0][kb]) + fabsf(oc[1][k] - oc[1][kb])
                            + fabsf(oc[2][k] - oc[2][kb]);
            const float sadm = (!EDGE || cv[k]) ? sad : 0.f;
            acc = fmaf(EXP2(fmaf(SC2, ss, L)), sadm, acc);
        }
    }
}

template<int DY, bool EDGE>
__device__ __forceinline__ void pairs_dyn(const float (&yc)[3][8], const float (&oc)[3][8],
                                          const float (&yb)[3][4], const float (&ob)[3][4],
                                          const bool (&cv)[8], float& acc)
{
    constexpr float L1[3] = { -20.99717945f, -20.99435890f, -20.99153288f }; // dy=1,[adx]
    constexpr float L2[3] = { -20.99435343f, -20.99153288f, -20.98870686f }; // dy=2,[adx]
#pragma unroll
    for (int dx = -2; dx <= 2; ++dx) {
        const int adx = dx < 0 ? -dx : dx;
        const float L = (DY == 1) ? L1[adx] : L2[adx];
#pragma unroll
        for (int p = 0; p < 4; ++p) {
            const int k = p + dx + 2;              // 0..7
            const float d0 = yc[0][k] - yb[0][p];
            const float d1 = yc[1][k] - yb[1][p];
            const float d2 = yc[2][k] - yb[2][p];
            const float ss = fmaf(d2, d2, fmaf(d1, d1, d0 * d0));
            const float sad = fabsf(oc[0][k] - ob[0][p]) + fabsf(oc[1][k] - ob[1][p])
                            + fabsf(oc[2][k] - ob[2][p]);
            const float sadm = (!EDGE || cv[k]) ? sad : 0.f;
            acc = fmaf(EXP2(fmaf(SC2, ss, L)), sadm, acc);
        }
    }
}

template<bool EDGE>
__device__ __forceinline__ float run_strip(const float* __restrict__ x,
                                           const float* __restrict__ op,
                                           int wq, int rb, int b, int lane,
                                           float4 (&B0)[9][64], float4 (&B1)[9][64])
{
    bool cv[8];
#pragma unroll
    for (int k = 0; k < 8; ++k) cv[k] = !EDGE || ((unsigned)(wq - 2 + k) < (unsigned)WW);

    const int fb0 = (b * 3 * HH + rb) * WW + (wq - 4);   // c=0, s=0 window base
    int mrow = (2 * rb + wq + 2) % 3;                    // fb0 % 3 (nonneg form)

    float Rc[3][5], Rb[3];
    float yp[2][3][4], opv[2][3][4];
    float yc[3][8], oc[3][8];
    float acc0 = 0.f, acc1 = 0.f;

    stage_x<EDGE>(x, fb0, B0);                           // prologue: row 0 -> B0

    // ---- s = 0 ----
    build_rot(mrow, Rc, Rb);
    row_phase<EDGE>(x, op, fb0, 0, 1, B0, B1, Rc, Rb, yc, oc, lane);
    pairs_dy0<EDGE>(yc, oc, cv, acc0);
    stash(yp[0], opv[0], yc, oc);
    // ---- s = 1 ----
    mrow = mod3s(mrow + 2);
    build_rot(mrow, Rc, Rb);
    row_phase<EDGE>(x, op, fb0, 1, 2, B1, B0, Rc, Rb, yc, oc, lane);
    pairs_dy0<EDGE>(yc, oc, cv, acc0);
    pairs_dyn<1, EDGE>(yc, oc, yp[0], opv[0], cv, acc1);
    stash(yp[1], opv[1], yc, oc);

#pragma unroll 1
    for (int s = 2; s < 10; s += 2) {
        // ---- row A = s (even): reads B0, stages s+1 -> B1 ----
        mrow = mod3s(mrow + 2);
        build_rot(mrow, Rc, Rb);
        const bool rokA = !EDGE || (rb + s) < HH;
        row_phase<EDGE>(x, op, fb0, s, s + 1, B0, B1, Rc, Rb, yc, oc, lane);
        if (s < 8) pairs_dy0<EDGE>(yc, oc, cv, acc0);
        if (rokA) {
            pairs_dyn<1, EDGE>(yc, oc, yp[1], opv[1], cv, acc0);   // base row s-1
            pairs_dyn<2, EDGE>(yc, oc, yp[0], opv[0], cv, acc1);   // base row s-2
        }
        if (s < 8) stash(yp[0], opv[0], yc, oc);
        // ---- row B = s+1 (odd): reads B1, stages min(s+2,9) -> B0 ----
        mrow = mod3s(mrow + 2);
        build_rot(mrow, Rc, Rb);
        const bool rokB = !EDGE || (rb + s + 1) < HH;
        row_phase<EDGE>(x, op, fb0, s + 1, (s + 2 < 10 ? s + 2 : 9), B1, B0,
                        Rc, Rb, yc, oc, lane);
        if (s + 1 < 8) pairs_dy0<EDGE>(yc, oc, cv, acc0);
        if (rokB) {
            if (s < 8) pairs_dyn<1, EDGE>(yc, oc, yp[0], opv[0], cv, acc0);  // base row s
            pairs_dyn<2, EDGE>(yc, oc, yp[1], opv[1], cv, acc1);             // base row s-1
        }
        if (s + 1 < 8) stash(yp[1], opv[1], yc, oc);
    }

    return acc0 + acc1;
}

__global__ __launch_bounds__(256)
void smooth_loss_kernel(const float* __restrict__ x, const float* __restrict__ op,
                        float* __restrict__ total)
{
    __shared__ float4 stage_buf[2][4][9][64];           // 72 KiB: [buf][wave][chunk][lane]
    __shared__ float s_part[4];

    const int tx  = threadIdx.x;                    // 0..31
    const int ty  = threadIdx.y;                    // 0..7
    const int tid = ty * 32 + tx;
    const int lane = tid & 63;
    const int wave = tid >> 6;
    const int bx  = blockIdx.x, by = blockIdx.y, b = blockIdx.z;
    const int wq  = bx * 128 + 4 * tx;              // first owned col
    const int rb  = by * 64 + 8 * ty;               // first owned row (<= 504)

    float acc;
    if ((bx == 1 || bx == 2) && by < 7)             // block-uniform branch
        acc = run_strip<false>(x, op, wq, rb, b, lane,
                               stage_buf[0][wave], stage_buf[1][wave]);
    else
        acc = run_strip<true>(x, op, wq, rb, b, lane,
                              stage_buf[0][wave], stage_buf[1][wave]);

    // ---- reduction: wave shuffle -> LDS -> one atomic per block ----
#pragma unroll
    for (int off = 32; off > 0; off >>= 1)
        acc += __shfl_down(acc, off, 64);

    if ((tid & 63) == 0) s_part[tid >> 6] = acc;
    __syncthreads();
    if (tid == 0)
        atomicAdd(total, s_part[0] + s_part[1] + s_part[2] + s_part[3]);
}

extern "C" void kernel_launch(void* const* d_in, const int* in_sizes, int n_in,
                              void* d_out, int out_size, void* d_ws, size_t ws_size,
                              hipStream_t stream) {
    const float* x  = (const float*)d_in[0];   // "input"  [16,3,512,512] fp32
    const float* op = (const float*)d_in[1];   // "output" [16,3,512,512] fp32
    float* total = (float*)d_out;              // scalar fp32

    hipMemsetAsync(total, 0, sizeof(float), stream);

    dim3 grid(4, 8, NB);                       // 512 blocks (2/CU)
    dim3 block(32, 8);                         // 256 threads; strip 4x8 each
    smooth_loss_kernel<<<grid, block, 0, stream>>>(x, op, total);
}

// Round 15
// 59.258 us; speedup vs baseline: 1.2365x; 1.0040x over previous
//
#include <hip/hip_runtime.h>

#define HH 512
#define WW 512
#define NB 16
#define NTOT (NB * 3 * HH * WW)     // 12582912
#define CHS (HH * WW)               // 262144, CHS % 3 == 1

// R15: LDS-dedup staging. Each lane stages ONE float4 per (channel,array) via
// global_load_lds (6 VMEM/row, was 18); lanes 0-3 stage the wave's 4 halo
// chunks (exec-masked) into slots 64..67. Windows read back via ds_read at
// lane+/-1 slots (halo slots for tx 0/31). Pipeline: read(s) [waits stage(s),
// issued one row earlier -> cheap], lgkmcnt(0), stage(s+2) issues, pairs(s)
// covers its latency. vmcnt(12) = one stage (12 ops) may remain in flight;
// in-order retirement => stage(s) done. vmcnt(0) at last row (nothing newer).
// ycc 5-tap rotated-coef (R8), exp-folded norm consts (R10).
// KEEP rolled `#pragma unroll 1` loop (R6). KEEP VGPR <= 128 (R9/R11/R13/R14)
// -> __launch_bounds__(256,4) forces the cap. KEEP 512 blocks (R12).

#define SC2 (-0.0072134752044448f)  // -1/(2*sigma^2) * log2(e), sigma=10

#if __has_builtin(__builtin_amdgcn_exp2f)
#define EXP2(v) __builtin_amdgcn_exp2f(v)
#else
#define EXP2(v) exp2f(v)
#endif

#define GLD_LDS(g, l) __builtin_amdgcn_global_load_lds(                      \
    (const __attribute__((address_space(1))) void*)(g),                      \
    (__attribute__((address_space(3))) void*)(l), 16, 0, 0)

typedef float4 WBuf[6][68];   // [ch*2+arr][slot]; slots 0..63 own, 64..67 halo

__device__ __forceinline__ int mod3s(int v) { return v >= 3 ? v - 3 : v; }

__device__ __forceinline__ void build_rot(int mrow, float (&Rc)[3][5], float (&Rb)[3])
{
    constexpr float T[3][5] = {
        { 0.f,     0.f,     0.257f, 0.564f, 0.098f },   // j=0
        { 0.f,    -0.148f, -0.291f, 0.439f, 0.f    },   // j=1
        { 0.439f, -0.368f, -0.071f, 0.f,    0.f    } }; // j=2
    constexpr float Tb[3] = { 16.f/255.f, 128.f/255.f, 128.f/255.f };
    const bool is1 = (mrow == 1);
    const bool is2 = (mrow == 2);
#pragma unroll
    for (int p = 0; p < 3; ++p) {
#pragma unroll
        for (int s = 0; s < 5; ++s) {
            const float v0 = T[p][s], v1 = T[(p+1)%3][s], v2 = T[(p+2)%3][s];
            Rc[p][s] = is1 ? v1 : (is2 ? v2 : v0);
        }
        Rb[p] = is1 ? Tb[(p+1)%3] : (is2 ? Tb[(p+2)%3] : Tb[p]);
    }
}

// stage row s: own chunk per (ch,arr) for all lanes; 4 halo chunks by lanes 0-3.
// 12 VMEM instructions total per call.
template<bool EDGE>
__device__ __forceinline__ void stage_row(const float* __restrict__ x,
                                          const float* __restrict__ op,
                                          int fb0, int s, WBuf& B,
                                          int hbase, int lane)
{
    const int ownf = fb0 + s * WW + 4;             // own chunk: cols wq..wq+3
#pragma unroll
    for (int c = 0; c < 3; ++c) {
        int f = ownf + c * CHS;
        if (EDGE) f = min(max(f, 0), NTOT - 4);
        GLD_LDS(x + f,  &B[2*c][0]);
        GLD_LDS(op + f, &B[2*c+1][0]);
    }
    if (lane < 4) {                                // halo: leftA,rightA,leftB,rightB
        const int hf0 = hbase + s * WW;
#pragma unroll
        for (int c = 0; c < 3; ++c) {
            int hf = hf0 + c * CHS;
            if (EDGE) hf = min(max(hf, 0), NTOT - 4);
            GLD_LDS(x + hf,  &B[2*c][64]);
            GLD_LDS(op + hf, &B[2*c+1][64]);
        }
    }
}

// read staged row from LDS, build yc (5-tap ycc) and oc windows
__device__ __forceinline__ void read_make(const WBuf& B, int lane, int lsl, int rsl,
                                          const float (&Rc)[3][5], const float (&Rb)[3],
                                          float (&yc)[3][8], float (&oc)[3][8])
{
#pragma unroll
    for (int c = 0; c < 3; ++c) {
        float xw[12];
        *(float4*)&xw[0] = B[2*c][lsl];            // cols wq-4..wq-1
        *(float4*)&xw[4] = B[2*c][lane];           // cols wq..wq+3
        *(float4*)&xw[8] = B[2*c][rsl];            // cols wq+4..wq+7
        const float2 ol  = *(const float2*)((const float*)&B[2*c+1][lsl] + 2);
        const float4 oo  = B[2*c+1][lane];
        const float2 orr = *(const float2*)&B[2*c+1][rsl];
        oc[c][0] = ol.x;  oc[c][1] = ol.y;
        oc[c][2] = oo.x;  oc[c][3] = oo.y; oc[c][4] = oo.z; oc[c][5] = oo.w;
        oc[c][6] = orr.x; oc[c][7] = orr.y;
#pragma unroll
        for (int k = 0; k < 8; ++k) {
            const int q = (c + k + 2) % 3;         // static after unroll
            float a = Rb[q];
#pragma unroll
            for (int t = 0; t < 5; ++t)
                a = fmaf(xw[k + t], Rc[q][t], a);
            yc[c][k] = a;
        }
    }
}

__device__ __forceinline__ void stash(float (&yb)[3][4], float (&ob)[3][4],
                                      const float (&yc)[3][8], const float (&oc)[3][8])
{
#pragma unroll
    for (int c = 0; c < 3; ++c)
#pragma unroll
        for (int p = 0; p < 4; ++p) { yb[c][p] = yc[c][p+2]; ob[c][p] = oc[c][p+2]; }
}

template<bool EDGE>
__device__ __forceinline__ void pairs_dy0(const float (&yc)[3][8], const float (&oc)[3][8],
                                          const bool (&cv)[8], float& acc)
{
    constexpr float L0[3] = { 0.f, -20.99717945f, -20.99435343f }; // [adx]
#pragma unroll
    for (int dx = 1; dx <= 2; ++dx) {
        const float L = L0[dx];
#pragma unroll
        for (int p = 0; p < 4; ++p) {
            const int k = p + dx + 2, kb = p + 2;
            const float d0 = yc[0][k] - yc[0][kb];
            const float d1 = yc[1][k] - yc[1][kb];
            const float d2 = yc[2][k] - yc[2][kb];
            const float ss = fmaf(d2, d2, fmaf(d1, d1, d0 * d0));
            const float sad = fabsf(oc[0][k] - oc[0][kb]) + fabsf(oc[1][k] - oc[1][kb])
                            + fabsf(oc[2][k] - oc[2][kb]);
            const float sadm = (!EDGE || cv[k]) ? sad : 0.f;
            acc = fmaf(EXP2(fmaf(SC2, ss, L)), sadm, acc);
        }
    }
}

template<int DY, bool EDGE>
__device__ __forceinline__ void pairs_dyn(const float (&yc)[3][8], const float (&oc)[3][8],
                                          const float (&yb)[3][4], const float (&ob)[3][4],
                                          const bool (&cv)[8], float& acc)
{
    constexpr float L1[3] = { -20.99717945f, -20.99435890f, -20.99153288f }; // dy=1,[adx]
    constexpr float L2[3] = { -20.99435343f, -20.99153288f, -20.98870686f }; // dy=2,[adx]
#pragma unroll
    for (int dx = -2; dx <= 2; ++dx) {
        const int adx = dx < 0 ? -dx : dx;
        const float L = (DY == 1) ? L1[adx] : L2[adx];
#pragma unroll
        for (int p = 0; p < 4; ++p) {
            const int k = p + dx + 2;              // 0..7
            const float d0 = yc[0][k] - yb[0][p];
            const float d1 = yc[1][k] - yb[1][p];
            const float d2 = yc[2][k] - yb[2][p];
            const float ss = fmaf(d2, d2, fmaf(d1, d1, d0 * d0));
            const float sad = fabsf(oc[0][k] - ob[0][p]) + fabsf(oc[1][k] - ob[1][p])
                            + fabsf(oc[2][k] - ob[2][p]);
            const float sadm = (!EDGE || cv[k]) ? sad : 0.f;
            acc = fmaf(EXP2(fmaf(SC2, ss, L)), sadm, acc);
        }
    }
}

template<bool EDGE>
__device__ __forceinline__ float run_strip(const float* __restrict__ x,
                                           const float* __restrict__ op,
                                           int wq, int rb, int b,
                                           int lane, int tx, int hbase,
                                           WBuf& B0, WBuf& B1)
{
    bool cv[8];
#pragma unroll
    for (int k = 0; k < 8; ++k) cv[k] = !EDGE || ((unsigned)(wq - 2 + k) < (unsigned)WW);

    const int fb0 = (b * 3 * HH + rb) * WW + (wq - 4);   // window base (cu=0)
    int mrow = (2 * rb + wq + 2) % 3;                    // fb0 % 3 (nonneg form)
    // LDS slots for the left/right window chunks (halo slots at tx edges)
    const int lsl = (tx == 0)  ? (64 + ((lane >> 5) << 1)) : lane - 1;
    const int rsl = (tx == 31) ? (65 + ((lane >> 5) << 1)) : lane + 1;

    float Rc[3][5], Rb[3];
    float yp[2][3][4], opv[2][3][4];
    float yc[3][8], oc[3][8];
    float acc0 = 0.f, acc1 = 0.f;

    stage_row<EDGE>(x, op, fb0, 0, B0, hbase, lane);     // prologue
    stage_row<EDGE>(x, op, fb0, 1, B1, hbase, lane);

    // ---- s = 0 ----
    build_rot(mrow, Rc, Rb);
    asm volatile("s_waitcnt vmcnt(12)" ::: "memory");    // stage(0) retired
    read_make(B0, lane, lsl, rsl, Rc, Rb, yc, oc);
    asm volatile("s_waitcnt lgkmcnt(0)" ::: "memory");   // reads done before overwrite
    stage_row<EDGE>(x, op, fb0, 2, B0, hbase, lane);
    pairs_dy0<EDGE>(yc, oc, cv, acc0);
    stash(yp[0], opv[0], yc, oc);
    // ---- s = 1 ----
    mrow = mod3s(mrow + 2);
    build_rot(mrow, Rc, Rb);
    asm volatile("s_waitcnt vmcnt(12)" ::: "memory");    // stage(1) retired
    read_make(B1, lane, lsl, rsl, Rc, Rb, yc, oc);
    asm volatile("s_waitcnt lgkmcnt(0)" ::: "memory");
    stage_row<EDGE>(x, op, fb0, 3, B1, hbase, lane);
    pairs_dy0<EDGE>(yc, oc, cv, acc0);
    pairs_dyn<1, EDGE>(yc, oc, yp[0], opv[0], cv, acc1);
    stash(yp[1], opv[1], yc, oc);

#pragma unroll 1
    for (int s = 2; s < 10; s += 2) {
        // ---- row A = s (buf0) ----
        mrow = mod3s(mrow + 2);
        build_rot(mrow, Rc, Rb);
        const bool rokA = !EDGE || (rb + s) < HH;
        asm volatile("s_waitcnt vmcnt(12)" ::: "memory");
        read_make(B0, lane, lsl, rsl, Rc, Rb, yc, oc);
        asm volatile("s_waitcnt lgkmcnt(0)" ::: "memory");
        if (s + 2 < 10) stage_row<EDGE>(x, op, fb0, s + 2, B0, hbase, lane);
        if (s < 8) pairs_dy0<EDGE>(yc, oc, cv, acc0);
        if (rokA) {
            pairs_dyn<1, EDGE>(yc, oc, yp[1], opv[1], cv, acc0);   // base row s-1
            pairs_dyn<2, EDGE>(yc, oc, yp[0], opv[0], cv, acc1);   // base row s-2
        }
        if (s < 8) stash(yp[0], opv[0], yc, oc);
        // ---- row B = s+1 (buf1) ----
        mrow = mod3s(mrow + 2);
        build_rot(mrow, Rc, Rb);
        const bool rokB = !EDGE || (rb + s + 1) < HH;
        if (s == 8) { asm volatile("s_waitcnt vmcnt(0)"  ::: "memory"); }  // nothing newer
        else        { asm volatile("s_waitcnt vmcnt(12)" ::: "memory"); }
        read_make(B1, lane, lsl, rsl, Rc, Rb, yc, oc);
        asm volatile("s_waitcnt lgkmcnt(0)" ::: "memory");
        if (s + 3 < 10) stage_row<EDGE>(x, op, fb0, s + 3, B1, hbase, lane);
        if (s + 1 < 8) pairs_dy0<EDGE>(yc, oc, cv, acc0);
        if (rokB) {
            if (s < 8) pairs_dyn<1, EDGE>(yc, oc, yp[0], opv[0], cv, acc0);  // base row s
            pairs_dyn<2, EDGE>(yc, oc, yp[1], opv[1], cv, acc1);             // base row s-1
        }
        if (s + 1 < 8) stash(yp[1], opv[1], yc, oc);
    }

    return acc0 + acc1;
}

__global__ __launch_bounds__(256, 4)   // force VGPR <= 128 (the recurring cliff)
void smooth_loss_kernel(const float* __restrict__ x, const float* __restrict__ op,
                        float* __restrict__ total)
{
    __shared__ float4 SB[2][4][6][68];              // 52224 B: [buf][wave][region][slot]
    __shared__ float s_part[4];

    const int tx   = threadIdx.x;                   // 0..31
    const int ty   = threadIdx.y;                   // 0..7
    const int tid  = ty * 32 + tx;
    const int lane = tid & 63;
    const int wave = tid >> 6;
    const int bx   = blockIdx.x, by = blockIdx.y, b = blockIdx.z;
    const int wq   = bx * 128 + 4 * tx;             // first owned col
    const int rb   = by * 64 + 8 * ty;              // first owned row (<= 504)

    // halo global base (used by lanes 0-3): {leftA,rightA,leftB,rightB}
    const int rbA   = by * 64 + 16 * wave;          // row A of this wave
    const int hbase = (b * 3) * CHS + rbA * WW + bx * 128
                    + ((lane & 2) ? 8 * WW : 0) + ((lane & 1) ? 128 : -4);

    float acc;
    if ((bx == 1 || bx == 2) && by < 7)             // interior: no clamps/selects
        acc = run_strip<false>(x, op, wq, rb, b, lane, tx, hbase,
                               SB[0][wave], SB[1][wave]);
    else
        acc = run_strip<true>(x, op, wq, rb, b, lane, tx, hbase,
                              SB[0][wave], SB[1][wave]);

    // ---- reduction: wave shuffle -> LDS -> one atomic per block ----
#pragma unroll
    for (int off = 32; off > 0; off >>= 1)
        acc += __shfl_down(acc, off, 64);

    if ((tid & 63) == 0) s_part[tid >> 6] = acc;
    __syncthreads();
    if (tid == 0)
        atomicAdd(total, s_part[0] + s_part[1] + s_part[2] + s_part[3]);
}

extern "C" void kernel_launch(void* const* d_in, const int* in_sizes, int n_in,
                              void* d_out, int out_size, void* d_ws, size_t ws_size,
                              hipStream_t stream) {
    const float* x  = (const float*)d_in[0];   // "input"  [16,3,512,512] fp32
    const float* op = (const float*)d_in[1];   // "output" [16,3,512,512] fp32
    float* total = (float*)d_out;              // scalar fp32

    hipMemsetAsync(total, 0, sizeof(float), stream);

    dim3 grid(4, 8, NB);                       // 512 blocks (2/CU)
    dim3 block(32, 8);                         // 256 threads; strip 4x8 each
    smooth_loss_kernel<<<grid, block, 0, stream>>>(x, op, total);
}

// Round 16
// 45.533 us; speedup vs baseline: 1.6093x; 1.3014x over previous
//
#include <hip/hip_runtime.h>

#define HH 512
#define WW 512
#define NB 16
#define NTOT (NB * 3 * HH * WW)     // 12582912
#define CHS (HH * WW)               // 262144, CHS % 3 == 1

// 4-wide x 8-tall strips, no LDS (except reduction). Rolling 2-row history.
// ycc[f] = x[f-j]*mat[0][j] + x[f-j+1]*mat[1][j] + x[f-j+2]*mat[2][j] + bias[j],
// j = f % 3 (reference's reshape(-1,3) @ mat over flat NCHW memory).
// 5-tap rotated-coef scheme (R8) + exp-folded norm consts (R10).
// R16: o window loaded as 2 UNALIGNED dwordx4 (fb+2, fb+6) instead of 3
// aligned -> 15 VMEM/row (was 18), zero register / zero VALU cost.
// 12 unique offsets, each counted twice in the reference -> factor 2 (in L*).
// KEEP rolled `#pragma unroll 1` loop (R6: full unroll = 256 VGPR + spills).
// KEEP VGPR <= 128 (R9/R11/R13/R14/R15: >128 -> occupancy halves -> regress).
// KEEP 512 blocks / 2 waves per SIMD (R12: 1 wave/SIMD hurts; R7: 4 no gain).

#define SC2 (-0.0072134752044448f)  // -1/(2*sigma^2) * log2(e), sigma=10

#if __has_builtin(__builtin_amdgcn_exp2f)
#define EXP2(v) __builtin_amdgcn_exp2f(v)
#else
#define EXP2(v) exp2f(v)
#endif

__device__ __forceinline__ int mod3s(int v) { return v >= 3 ? v - 3 : v; }

__device__ __forceinline__ void build_rot(int mrow, float (&Rc)[3][5], float (&Rb)[3])
{
    constexpr float T[3][5] = {
        { 0.f,     0.f,     0.257f, 0.564f, 0.098f },   // j=0
        { 0.f,    -0.148f, -0.291f, 0.439f, 0.f    },   // j=1
        { 0.439f, -0.368f, -0.071f, 0.f,    0.f    } }; // j=2
    constexpr float Tb[3] = { 16.f/255.f, 128.f/255.f, 128.f/255.f };
    const bool is1 = (mrow == 1);
    const bool is2 = (mrow == 2);
#pragma unroll
    for (int p = 0; p < 3; ++p) {
#pragma unroll
        for (int s = 0; s < 5; ++s) {
            const float v0 = T[p][s], v1 = T[(p+1)%3][s], v2 = T[(p+2)%3][s];
            Rc[p][s] = is1 ? v1 : (is2 ? v2 : v0);
        }
        Rb[p] = is1 ? Tb[(p+1)%3] : (is2 ? Tb[(p+2)%3] : Tb[p]);
    }
}

template<bool EDGE>
__device__ __forceinline__ void load_make(const float* __restrict__ x,
                                          const float* __restrict__ op,
                                          int fbase,
                                          const float (&Rc)[3][5], const float (&Rb)[3],
                                          float (&yc)[3][8], float (&oc)[3][8])
{
#pragma unroll
    for (int c = 0; c < 3; ++c) {
        const int fb = fbase + c * CHS;
        int f0 = fb, f1 = fb + 4, f2 = fb + 8;
        int g0 = fb + 2, g1 = fb + 6;              // o window: 2 unaligned chunks
        if (EDGE) {
            f0 = min(max(f0, 0), NTOT - 4);
            f1 = min(max(f1, 0), NTOT - 4);
            f2 = min(max(f2, 0), NTOT - 4);
            g0 = min(max(g0, 0), NTOT - 4);
            g1 = min(max(g1, 0), NTOT - 4);
        }
        float xw[12], ow[8];
        *(float4*)&xw[0] = *(const float4*)(x + f0);
        *(float4*)&xw[4] = *(const float4*)(x + f1);
        *(float4*)&xw[8] = *(const float4*)(x + f2);
        *(float4*)&ow[0] = *(const float4*)(op + g0);
        *(float4*)&ow[4] = *(const float4*)(op + g1);
#pragma unroll
        for (int k = 0; k < 8; ++k) {
            const int q = (c + k + 2) % 3;         // static after unroll
            float a = Rb[q];
#pragma unroll
            for (int s = 0; s < 5; ++s)
                a = fmaf(xw[k + s], Rc[q][s], a);
            yc[c][k] = a;
            oc[c][k] = ow[k];                      // window col k+2 == ow[k]
        }
    }
}

__device__ __forceinline__ void stash(float (&yb)[3][4], float (&ob)[3][4],
                                      const float (&yc)[3][8], const float (&oc)[3][8])
{
#pragma unroll
    for (int c = 0; c < 3; ++c)
#pragma unroll
        for (int p = 0; p < 4; ++p) { yb[c][p] = yc[c][p+2]; ob[c][p] = oc[c][p+2]; }
}

template<bool EDGE>
__device__ __forceinline__ void pairs_dy0(const float (&yc)[3][8], const float (&oc)[3][8],
                                          const bool (&cv)[8], float& acc)
{
    constexpr float L0[3] = { 0.f, -20.99717945f, -20.99435343f }; // [adx]
#pragma unroll
    for (int dx = 1; dx <= 2; ++dx) {
        const float L = L0[dx];
#pragma unroll
        for (int p = 0; p < 4; ++p) {
            const int k = p + dx + 2, kb = p + 2;
            const float d0 = yc[0][k] - yc[0][kb];
            const float d1 = yc[1][k] - yc[1][kb];
            const float d2 = yc[2][k] - yc[2][kb];
            const float ss = fmaf(d2, d2, fmaf(d1, d1, d0 * d0));
            const float sad = fabsf(oc[0][k] - oc[0][kb]) + fabsf(oc[1][k] - oc[1][kb])
                            + fabsf(oc[2][k] - oc[2][kb]);
            const float sadm = (!EDGE || cv[k]) ? sad : 0.f;
            acc = fmaf(EXP2(fmaf(SC2, ss, L)), sadm, acc);
        }
    }
}

template<int DY, bool EDGE>
__device__ __forceinline__ void pairs_dyn(const float (&yc)[3][8], const float (&oc)[3][8],
                                          const float (&yb)[3][4], const float (&ob)[3][4],
                                          const bool (&cv)[8], float& acc)
{
    constexpr float L1[3] = { -20.99717945f, -20.99435890f, -20.99153288f }; // dy=1,[adx]
    constexpr float L2[3] = { -20.99435343f, -20.99153288f, -20.98870686f }; // dy=2,[adx]
#pragma unroll
    for (int dx = -2; dx <= 2; ++dx) {
        const int adx = dx < 0 ? -dx : dx;
        const float L = (DY == 1) ? L1[adx] : L2[adx];
#pragma unroll
        for (int p = 0; p < 4; ++p) {
            const int k = p + dx + 2;              // 0..7
            const float d0 = yc[0][k] - yb[0][p];
            const float d1 = yc[1][k] - yb[1][p];
            const float d2 = yc[2][k] - yb[2][p];
            const float ss = fmaf(d2, d2, fmaf(d1, d1, d0 * d0));
            const float sad = fabsf(oc[0][k] - ob[0][p]) + fabsf(oc[1][k] - ob[1][p])
                            + fabsf(oc[2][k] - ob[2][p]);
            const float sadm = (!EDGE || cv[k]) ? sad : 0.f;
            acc = fmaf(EXP2(fmaf(SC2, ss, L)), sadm, acc);
        }
    }
}

template<bool EDGE>
__device__ __forceinline__ float run_strip(const float* __restrict__ x,
                                           const float* __restrict__ op,
                                           int wq, int rb, int b)
{
    bool cv[8];
#pragma unroll
    for (int k = 0; k < 8; ++k) cv[k] = !EDGE || ((unsigned)(wq - 2 + k) < (unsigned)WW);

    const int fb0 = (b * 3 * HH + rb) * WW + (wq - 4);   // c=0, s=0 window base
    int mrow = (2 * rb + wq + 2) % 3;                    // fb0 % 3 (nonneg form)

    float Rc[3][5], Rb[3];
    float yp[2][3][4], opv[2][3][4];
    float yc[3][8], oc[3][8];
    float acc0 = 0.f, acc1 = 0.f;

    // ---- s = 0 ----
    build_rot(mrow, Rc, Rb);
    load_make<EDGE>(x, op, fb0, Rc, Rb, yc, oc);
    pairs_dy0<EDGE>(yc, oc, cv, acc0);
    stash(yp[0], opv[0], yc, oc);
    // ---- s = 1 ----
    mrow = mod3s(mrow + 2);
    build_rot(mrow, Rc, Rb);
    load_make<EDGE>(x, op, fb0 + WW, Rc, Rb, yc, oc);
    pairs_dy0<EDGE>(yc, oc, cv, acc0);
    pairs_dyn<1, EDGE>(yc, oc, yp[0], opv[0], cv, acc1);
    stash(yp[1], opv[1], yc, oc);

#pragma unroll 1
    for (int s = 2; s < 10; s += 2) {
        // ---- row A = s: slot0 holds s-2, slot1 holds s-1 ----
        mrow = mod3s(mrow + 2);
        build_rot(mrow, Rc, Rb);
        const bool rokA = !EDGE || (rb + s) < HH;
        load_make<EDGE>(x, op, fb0 + s * WW, Rc, Rb, yc, oc);
        if (s < 8) pairs_dy0<EDGE>(yc, oc, cv, acc0);
        if (rokA) {
            pairs_dyn<1, EDGE>(yc, oc, yp[1], opv[1], cv, acc0);   // base row s-1
            pairs_dyn<2, EDGE>(yc, oc, yp[0], opv[0], cv, acc1);   // base row s-2
        }
        if (s < 8) stash(yp[0], opv[0], yc, oc);
        // ---- row B = s+1: slot0 holds s, slot1 holds s-1 ----
        mrow = mod3s(mrow + 2);
        build_rot(mrow, Rc, Rb);
        const bool rokB = !EDGE || (rb + s + 1) < HH;
        load_make<EDGE>(x, op, fb0 + (s + 1) * WW, Rc, Rb, yc, oc);
        if (s + 1 < 8) pairs_dy0<EDGE>(yc, oc, cv, acc0);
        if (rokB) {
            if (s < 8) pairs_dyn<1, EDGE>(yc, oc, yp[0], opv[0], cv, acc0);  // base row s
            pairs_dyn<2, EDGE>(yc, oc, yp[1], opv[1], cv, acc1);             // base row s-1
        }
        if (s + 1 < 8) stash(yp[1], opv[1], yc, oc);
    }

    return acc0 + acc1;
}

__global__ __launch_bounds__(256)
void smooth_loss_kernel(const float* __restrict__ x, const float* __restrict__ op,
                        float* __restrict__ total)
{
    const int tx  = threadIdx.x;                    // 0..31
    const int ty  = threadIdx.y;                    // 0..7
    const int tid = ty * 32 + tx;
    const int bx  = blockIdx.x, by = blockIdx.y, b = blockIdx.z;
    const int wq  = bx * 128 + 4 * tx;              // first owned col
    const int rb  = by * 64 + 8 * ty;               // first owned row (<= 504)

    // interior blocks (44%): windows never touch image edges -> no clamps/selects
    float acc;
    if ((bx == 1 || bx == 2) && by < 7)             // block-uniform branch
        acc = run_strip<false>(x, op, wq, rb, b);
    else
        acc = run_strip<true>(x, op, wq, rb, b);

    // ---- reduction: wave shuffle -> LDS -> one atomic per block ----
#pragma unroll
    for (int off = 32; off > 0; off >>= 1)
        acc += __shfl_down(acc, off, 64);

    __shared__ float s_part[4];
    if ((tid & 63) == 0) s_part[tid >> 6] = acc;
    __syncthreads();
    if (tid == 0)
        atomicAdd(total, s_part[0] + s_part[1] + s_part[2] + s_part[3]);
}

extern "C" void kernel_launch(void* const* d_in, const int* in_sizes, int n_in,
                              void* d_out, int out_size, void* d_ws, size_t ws_size,
                              hipStream_t stream) {
    const float* x  = (const float*)d_in[0];   // "input"  [16,3,512,512] fp32
    const float* op = (const float*)d_in[1];   // "output" [16,3,512,512] fp32
    float* total = (float*)d_out;              // scalar fp32

    hipMemsetAsync(total, 0, sizeof(float), stream);

    dim3 grid(4, 8, NB);                       // 512 blocks (2/CU)
    dim3 block(32, 8);                         // 256 threads; strip 4x8 each
    smooth_loss_kernel<<<grid, block, 0, stream>>>(x, op, total);
}